// Round 8
// baseline (2992.875 us; speedup 1.0000x reference)
//
#include <hip/hip_runtime.h>
#include <cstdint>
#include <cstddef>

#define TPB 256

typedef __attribute__((ext_vector_type(8))) short bf16x8;
typedef __attribute__((ext_vector_type(4))) float f4acc;

// ---------------- index-building kernels ----------------

static __global__ void kscatter(int* __restrict__ grid, const int* __restrict__ coords,
                                int N, int S) {
    int i = blockIdx.x * blockDim.x + threadIdx.x;
    if (i >= N) return;
    int x = coords[3 * i], y = coords[3 * i + 1], z = coords[3 * i + 2];
    grid[(x * S + y) * S + z] = i;
}

// transposed neighbor table: nbrT[k*N + n]; invalid = -1
static __global__ void knbr27(int* __restrict__ nbrT, const int* __restrict__ coords,
                              const int* __restrict__ grid, int N, int S) {
    int t = blockIdx.x * blockDim.x + threadIdx.x;
    if (t >= N * 27) return;
    int n = t / 27, k = t - 27 * n;
    int x = coords[3 * n]     + (k / 9) - 1;
    int y = coords[3 * n + 1] + ((k / 3) % 3) - 1;
    int z = coords[3 * n + 2] + (k % 3) - 1;
    int v = -1;
    if ((unsigned)x < (unsigned)S && (unsigned)y < (unsigned)S && (unsigned)z < (unsigned)S)
        v = grid[(x * S + y) * S + z];
    nbrT[(size_t)k * N + n] = v;
}

static __global__ void kdown8(int* __restrict__ dnT, const int* __restrict__ coords,
                              const int* __restrict__ grid, int M, int S_f) {
    int t = blockIdx.x * blockDim.x + threadIdx.x;
    if (t >= M * 8) return;
    int n = t >> 3, k = t & 7;
    int x = coords[3 * n] * 2     + ((k >> 2) & 1);
    int y = coords[3 * n + 1] * 2 + ((k >> 1) & 1);
    int z = coords[3 * n + 2] * 2 + (k & 1);
    dnT[(size_t)k * M + n] = grid[(x * S_f + y) * S_f + z];
}

static __global__ void kup(int* __restrict__ up, const int* __restrict__ cf,
                           const int* __restrict__ gc, int N, int Sc) {
    int n = blockIdx.x * blockDim.x + threadIdx.x;
    if (n >= N) return;
    int x = cf[3 * n] >> 2, y = cf[3 * n + 1] >> 2, z = cf[3 * n + 2] >> 2;
    up[n] = gc[(x * Sc + y) * Sc + z];
}

// W[K][A][B] -> Wt[K][B][A] fp32 (for fp32-path convs)
static __global__ void ktrans(float* __restrict__ Wt, const float* __restrict__ W,
                              int K, int A, int B) {
    int t = blockIdx.x * blockDim.x + threadIdx.x;
    if (t >= K * A * B) return;
    int a = t % A, b = (t / A) % B, k = t / (A * B);
    Wt[t] = W[(k * A + a) * B + b];
}

// exact 3-way bf16 truncation split
__device__ __forceinline__ void split3(float v, unsigned short& h0, unsigned short& h1,
                                       unsigned short& h2) {
    unsigned u = __float_as_uint(v);
    unsigned t0 = u & 0xFFFF0000u;
    float r1 = v - __uint_as_float(t0);
    unsigned u1 = __float_as_uint(r1) & 0xFFFF0000u;
    float r2 = r1 - __uint_as_float(u1);
    unsigned u2 = __float_as_uint(r2) & 0xFFFF0000u;
    h0 = (unsigned short)(t0 >> 16);
    h1 = (unsigned short)(u1 >> 16);
    h2 = (unsigned short)(u2 >> 16);
}

// W[K][A][B] fp32 -> Wp[k][b][3][Apad] bf16 planes
static __global__ void kwprep(unsigned short* __restrict__ Wp, const float* __restrict__ W,
                              int K, int A, int B, int Apad) {
    int t = blockIdx.x * blockDim.x + threadIdx.x;
    if (t >= K * B * Apad) return;
    int a = t % Apad, rem = t / Apad, b = rem % B, k = rem / B;
    float v = (a < A) ? W[((size_t)k * A + a) * B + b] : 0.0f;
    unsigned short h0, h1, h2;
    split3(v, h0, h1, h2);
    size_t base = (((size_t)k * B + b) * 3) * Apad + a;
    Wp[base] = h0; Wp[base + Apad] = h1; Wp[base + 2 * Apad] = h2;
}

// feature prep: x[N x A] fp32 (+BN-ReLU or att) -> P[n][3][Apad] bf16 planes
// mode: 0 plain, 1 BN-ReLU, 2 att-multiply
static __global__ void kfprep(unsigned short* __restrict__ P, const float* __restrict__ x,
                              int N, int A, int Apad, const double* __restrict__ st,
                              const float* __restrict__ g, const float* __restrict__ b,
                              const float* __restrict__ att, int mode, int nstat) {
    int t = blockIdx.x * blockDim.x + threadIdx.x;
    if (t >= N * Apad) return;
    int a = t % Apad, n = t / Apad;
    float v = 0.0f;
    if (a < A) {
        v = x[(size_t)n * A + a];
        if (mode == 1) {
            double invN = 1.0 / (double)nstat;
            double mu = st[a] * invN;
            double var = st[80 + a] * invN - mu * mu;
            float s = g[a] * rsqrtf((float)var + 1e-4f);
            v = fmaxf(fmaf(v, s, b[a] - (float)mu * s), 0.0f);
        } else if (mode == 2) {
            v *= att[n];
        }
    }
    unsigned short h0, h1, h2;
    split3(v, h0, h1, h2);
    size_t base = ((size_t)n * 3) * Apad + a;
    P[base] = h0; P[base + Apad] = h1; P[base + 2 * Apad] = h2;
}

// ---------------- BN stats ----------------

static __global__ void kstats(double* __restrict__ st, const float* __restrict__ x,
                              int N, int C) {
    extern __shared__ double sh[];
    int tid = threadIdx.x;
    int c = tid % C, rl = tid / C;
    double s = 0.0, q = 0.0;
    int base = blockIdx.x * 256 + rl * 64;
    for (int it = 0; it < 64; it++) {
        int r = base + it;
        if (r < N) {
            double v = (double)x[(size_t)r * C + c];
            s += v;
            q = fma(v, v, q);
        }
    }
    double* ss = sh;
    double* sq = sh + 4 * C;
    ss[tid] = s; sq[tid] = q;
    __syncthreads();
    if (tid < C) {
        double S = ss[tid] + ss[tid + C] + ss[tid + 2 * C] + ss[tid + 3 * C];
        double Q = sq[tid] + sq[tid + C] + sq[tid + 2 * C] + sq[tid + 3 * C];
        atomicAdd(&st[tid], S);
        atomicAdd(&st[80 + tid], Q);
    }
}

// ---------------- MFMA tile conv (3-plane exact bf16 split, 6 cross terms) ----
// out[n][b] = sum_k sum_a feat[nbrT[k][n]][a] * W[k][a][b]
// P: packed features [n][3][Apad] bf16; Wp: [k][b][3][Apad] bf16.
// Block: 256 thr = 4 waves; block computes 64 rows x B; wave w rows [16w,16w+16).
// EPI: 0 = store, 1 = store + res, 2 = atomicAdd (KG>1 partials).

template <int A, int B, int TAPS, int KG, int EPI>
__launch_bounds__(256)
static __global__ void kconvm(float* __restrict__ out, const unsigned short* __restrict__ P,
                              const int* __restrict__ nbrT, const unsigned short* __restrict__ Wp,
                              const float* __restrict__ res, int N) {
    constexpr int Apad = ((A + 31) / 32) * 32;
    constexpr int PADA = Apad + 8;            // bf16 units; breaks pitch conflicts
    constexpr int KC = Apad / 32;
    constexpr int NC = B / 16;
    constexpr int TRB = 64;
    constexpr int SEGP = Apad / 8;            // f4 per plane-row
    constexpr int SEGR = 3 * SEGP;            // f4 per packed row
    constexpr int GQ = TRB * SEGR;
    constexpr int WQ = B * SEGR;
    constexpr int KPG = (TAPS + KG - 1) / KG;

    __shared__ __attribute__((aligned(16))) unsigned short Gs[3][TRB][PADA];
    __shared__ __attribute__((aligned(16))) unsigned short Wsh[3][B][PADA];

    const int tid = threadIdx.x;
    const int wave = tid >> 6, lane = tid & 63;
    const int m = lane & 15, q = lane >> 4;
    const int row0 = blockIdx.x * TRB;
    const int k0 = (KG > 1) ? blockIdx.y * KPG : 0;
    const int k1 = (KG > 1) ? ((k0 + KPG < TAPS) ? k0 + KPG : TAPS) : TAPS;
    const float4* Pf4 = (const float4*)P;

    f4acc acc[NC];
#pragma unroll
    for (int nc = 0; nc < NC; nc++) acc[nc] = (f4acc){0.f, 0.f, 0.f, 0.f};

    for (int k = k0; k < k1; k++) {
        __syncthreads();
        // stage weight tap (3 planes)
        const float4* wk4 = (const float4*)(Wp + (size_t)k * B * 3 * Apad);
#pragma unroll
        for (int it = 0; it < (WQ + 255) / 256; it++) {
            int idx = tid + it * 256;
            if (WQ % 256 == 0 || idx < WQ) {
                int br = idx / SEGR, rem = idx - br * SEGR;
                int p = rem / SEGP, s = rem - p * SEGP;
                *(float4*)&Wsh[p][br][s * 8] = wk4[idx];
            }
        }
        // gather 64 packed feature rows
#pragma unroll
        for (int it = 0; it < (GQ + 255) / 256; it++) {
            int idx = tid + it * 256;
            if (GQ % 256 == 0 || idx < GQ) {
                int rr = idx / SEGR, rem = idx - rr * SEGR;
                int p = rem / SEGP, s = rem - p * SEGP;
                int r = row0 + rr;
                int id = (r < N) ? nbrT[(size_t)k * N + r] : -1;
                float4 v = Pf4[(size_t)(id < 0 ? 0 : id) * SEGR + rem];
                if (id < 0) v = make_float4(0.f, 0.f, 0.f, 0.f);
                *(float4*)&Gs[p][rr][s * 8] = v;
            }
        }
        __syncthreads();
        // MFMA compute from LDS
#pragma unroll
        for (int kc = 0; kc < KC; kc++) {
            int ko = kc * 32 + q * 8;
            bf16x8 a0 = *(const bf16x8*)&Gs[0][wave * 16 + m][ko];
            bf16x8 a1 = *(const bf16x8*)&Gs[1][wave * 16 + m][ko];
            bf16x8 a2 = *(const bf16x8*)&Gs[2][wave * 16 + m][ko];
#pragma unroll
            for (int nc = 0; nc < NC; nc++) {
                int brow = nc * 16 + m;
                bf16x8 b0 = *(const bf16x8*)&Wsh[0][brow][ko];
                bf16x8 b1 = *(const bf16x8*)&Wsh[1][brow][ko];
                bf16x8 b2 = *(const bf16x8*)&Wsh[2][brow][ko];
                acc[nc] = __builtin_amdgcn_mfma_f32_16x16x32_bf16(a0, b0, acc[nc], 0, 0, 0);
                acc[nc] = __builtin_amdgcn_mfma_f32_16x16x32_bf16(a0, b1, acc[nc], 0, 0, 0);
                acc[nc] = __builtin_amdgcn_mfma_f32_16x16x32_bf16(a1, b0, acc[nc], 0, 0, 0);
                acc[nc] = __builtin_amdgcn_mfma_f32_16x16x32_bf16(a0, b2, acc[nc], 0, 0, 0);
                acc[nc] = __builtin_amdgcn_mfma_f32_16x16x32_bf16(a1, b1, acc[nc], 0, 0, 0);
                acc[nc] = __builtin_amdgcn_mfma_f32_16x16x32_bf16(a2, b0, acc[nc], 0, 0, 0);
            }
        }
    }

    // epilogue: C/D mapping col=lane&15, row=(lane>>4)*4+reg (m89-verified)
#pragma unroll
    for (int nc = 0; nc < NC; nc++) {
#pragma unroll
        for (int r = 0; r < 4; r++) {
            int row = row0 + wave * 16 + q * 4 + r;
            if (row < N) {
                size_t idx = (size_t)row * B + nc * 16 + m;
                if (EPI == 2) atomicAdd(&out[idx], acc[nc][r]);
                else if (EPI == 1) out[idx] = acc[nc][r] + res[idx];
                else out[idx] = acc[nc][r];
            }
        }
    }
}

// ---------------- fp32 LDS-staged tile conv (A=16 / B=80 shapes) ----------------
// MODE: 0 plain, 1 BN-ReLU staged, 2 BN-ReLU + residual (out==res content), 3 att

template <int A, int B, int TAPS, int TR, int TX, int KG, int MODE>
__launch_bounds__(256)
static __global__ void kconv(float* __restrict__ out, const float* __restrict__ feat,
                             const int* __restrict__ nbrT, const float* __restrict__ Wt,
                             const float* __restrict__ att, const double* __restrict__ st,
                             const float* __restrict__ gg, const float* __restrict__ bb,
                             int N, int nstat) {
    constexpr bool BN = (MODE == 1 || MODE == 2);
    constexpr bool ADD = (MODE == 2);
    constexpr bool MUL = (MODE == 3);
    constexpr int A4 = A / 4;
    constexpr int PITCH = A + 4;
    constexpr int TY = 256 / TX;
    constexpr int RT = TR / TY;
    constexpr int CT = B / TX;
    constexpr int GQ = TR * A4;
    constexpr int WQ = B * A4;
    constexpr int KPG = (TAPS + KG - 1) / KG;

    __shared__ __attribute__((aligned(16))) float gs[TR * PITCH];
    __shared__ __attribute__((aligned(16))) float wsh[B * PITCH];
    __shared__ float scs[A], bhs[A];

    const int tid = threadIdx.x;
    const int tx = tid % TX, ty = tid / TX;
    const int row0 = blockIdx.x * TR;
    const int k0 = (KG > 1) ? blockIdx.y * KPG : 0;
    const int k1 = (KG > 1) ? ((k0 + KPG < TAPS) ? k0 + KPG : TAPS) : TAPS;
    const float4* f4 = (const float4*)feat;

    if (BN && tid < A) {
        double invN = 1.0 / (double)nstat;
        double mu = st[tid] * invN;
        double var = st[80 + tid] * invN - mu * mu;
        float s = gg[tid] * rsqrtf((float)var + 1e-4f);
        scs[tid] = s;
        bhs[tid] = bb[tid] - (float)mu * s;
    }

    float acc[RT][CT];
#pragma unroll
    for (int i = 0; i < RT; i++) {
        int r = row0 + ty + TY * i;
#pragma unroll
        for (int j = 0; j < CT; j++)
            acc[i][j] = (ADD && KG == 1 && r < N) ? out[(size_t)r * B + tx + TX * j] : 0.0f;
    }

    for (int k = k0; k < k1; k++) {
        __syncthreads();
        const float4* wk = (const float4*)(Wt + (size_t)k * B * A);
#pragma unroll
        for (int it = 0; it < (WQ + 255) / 256; it++) {
            int idx = tid + it * 256;
            if (WQ % 256 == 0 || idx < WQ) {
                int br = idx / A4, seg = idx - br * A4;
                *(float4*)&wsh[br * PITCH + seg * 4] = wk[idx];
            }
        }
#pragma unroll
        for (int it = 0; it < (GQ + 255) / 256; it++) {
            int idx = tid + it * 256;
            if (GQ % 256 == 0 || idx < GQ) {
                int rr = idx / A4, seg = idx - rr * A4;
                int r = row0 + rr;
                int id = (r < N) ? nbrT[(size_t)k * N + r] : -1;
                float4 v = f4[(size_t)(id < 0 ? 0 : id) * A4 + seg];
                if (BN) {
                    int c0 = seg * 4;
                    v.x = fmaxf(fmaf(v.x, scs[c0 + 0], bhs[c0 + 0]), 0.f);
                    v.y = fmaxf(fmaf(v.y, scs[c0 + 1], bhs[c0 + 1]), 0.f);
                    v.z = fmaxf(fmaf(v.z, scs[c0 + 2], bhs[c0 + 2]), 0.f);
                    v.w = fmaxf(fmaf(v.w, scs[c0 + 3], bhs[c0 + 3]), 0.f);
                }
                if (MUL) {
                    float mm = (id < 0) ? 0.f : att[id];
                    v.x *= mm; v.y *= mm; v.z *= mm; v.w *= mm;
                }
                if (id < 0) v = make_float4(0.f, 0.f, 0.f, 0.f);
                *(float4*)&gs[rr * PITCH + seg * 4] = v;
            }
        }
        __syncthreads();
#pragma unroll
        for (int ac = 0; ac < A4; ac++) {
            float4 w[CT];
#pragma unroll
            for (int j = 0; j < CT; j++)
                w[j] = *(const float4*)&wsh[(tx + TX * j) * PITCH + ac * 4];
            float4 g[RT];
#pragma unroll
            for (int i = 0; i < RT; i++)
                g[i] = *(const float4*)&gs[(ty + TY * i) * PITCH + ac * 4];
#pragma unroll
            for (int i = 0; i < RT; i++)
#pragma unroll
                for (int j = 0; j < CT; j++) {
                    acc[i][j] = fmaf(g[i].x, w[j].x, acc[i][j]);
                    acc[i][j] = fmaf(g[i].y, w[j].y, acc[i][j]);
                    acc[i][j] = fmaf(g[i].z, w[j].z, acc[i][j]);
                    acc[i][j] = fmaf(g[i].w, w[j].w, acc[i][j]);
                }
        }
    }

#pragma unroll
    for (int i = 0; i < RT; i++) {
        int r = row0 + ty + TY * i;
        if (r < N) {
#pragma unroll
            for (int j = 0; j < CT; j++) {
                if (KG > 1) atomicAdd(&out[(size_t)r * B + tx + TX * j], acc[i][j]);
                else out[(size_t)r * B + tx + TX * j] = acc[i][j];
            }
        }
    }
}

// input layer: A=1, B=16
static __global__ void kconv_in(float* __restrict__ out, const float* __restrict__ f,
                                const int* __restrict__ nbrT, const float* __restrict__ W,
                                int N) {
    int t = blockIdx.x * blockDim.x + threadIdx.x;
    if (t >= N * 4) return;
    int n = t >> 2, bq = t & 3;
    float4 acc = make_float4(0.f, 0.f, 0.f, 0.f);
    const float4* W4 = (const float4*)W;
    for (int k = 0; k < 27; k++) {
        int id = nbrT[(size_t)k * N + n];
        if (id < 0) continue;
        float v = f[id];
        float4 w = W4[k * 4 + bq];
        acc.x = fmaf(v, w.x, acc.x);
        acc.y = fmaf(v, w.y, acc.y);
        acc.z = fmaf(v, w.z, acc.z);
        acc.w = fmaf(v, w.w, acc.w);
    }
    ((float4*)out)[n * 4 + bq] = acc;
}

// ---------------- heads / epilogue ----------------

static __global__ void kscores(float* __restrict__ sc, const float* __restrict__ x,
                               const float* __restrict__ w, int N, int C) {
    int n = blockIdx.x * blockDim.x + threadIdx.x;
    if (n >= N) return;
    float s0 = 0.0f, s1 = 0.0f;
    const float* xr = x + (size_t)n * C;
    for (int c = 0; c < C; c++) {
        float v = xr[c];
        s0 = fmaf(v, w[2 * c], s0);
        s1 = fmaf(v, w[2 * c + 1], s1);
    }
    sc[2 * n] = s0;
    sc[2 * n + 1] = s1;
}

static __global__ void katt(float* __restrict__ att, const int* __restrict__ up,
                            const float* __restrict__ sc, int N) {
    int n = blockIdx.x * blockDim.x + threadIdx.x;
    if (n >= N) return;
    int p = up[n];
    att[n] = (sc[2 * p + 1] > sc[2 * p]) ? 1.0f : 0.0f;
}

static __global__ void kout0(float* __restrict__ out, const float* __restrict__ z,
                             const float* __restrict__ pw, const float* __restrict__ sw,
                             int N) {
    int n = blockIdx.x * blockDim.x + threadIdx.x;
    if (n >= N) return;
    float o0 = 0, o1 = 0, o2 = 0, o3 = 0, o4 = 0;
    const float* zr = z + (size_t)n * 16;
#pragma unroll
    for (int c = 0; c < 16; c++) {
        float v = zr[c];
        o0 = fmaf(v, pw[3 * c], o0);
        o1 = fmaf(v, pw[3 * c + 1], o1);
        o2 = fmaf(v, pw[3 * c + 2], o2);
        o3 = fmaf(v, sw[2 * c], o3);
        o4 = fmaf(v, sw[2 * c + 1], o4);
    }
    float* r = out + (size_t)n * 5;
    r[0] = o0; r[1] = o1; r[2] = o2; r[3] = o3; r[4] = o4;
}

static __global__ void koutc(float* __restrict__ out, const int* __restrict__ coords,
                             const float* __restrict__ sc, int N) {
    int n = blockIdx.x * blockDim.x + threadIdx.x;
    if (n >= N) return;
    float* r = out + (size_t)n * 5;
    r[0] = (float)coords[3 * n];
    r[1] = (float)coords[3 * n + 1];
    r[2] = (float)coords[3 * n + 2];
    r[3] = sc[2 * n];
    r[4] = sc[2 * n + 1];
}

// ---------------- host helpers ----------------

static inline int cdiv(long a, int b) { return (int)((a + b - 1) / b); }
static inline int apad(int A) { return ((A + 31) / 32) * 32; }

// fp32-path dispatcher
static void convf(hipStream_t s, float* out, const float* feat, const int* nbrT,
                  const float* Wt, int N, int A, int B, int TAPS, int mode,
                  const float* att, const double* st, const float* g, const float* b,
                  int nstat) {
#define CASE(AA, BB, TT, TRR, TXX, KGG)                                                    \
    else if (A == AA && B == BB && TAPS == TT) {                                           \
        if (KGG > 1 && mode != 2) hipMemsetAsync(out, 0, (size_t)N * BB * 4, s);           \
        dim3 gr(cdiv(N, TRR), KGG), blk(256);                                              \
        if (mode == 0) kconv<AA, BB, TT, TRR, TXX, KGG, 0><<<gr, blk, 0, s>>>(out, feat, nbrT, Wt, att, st, g, b, N, nstat); \
        else if (mode == 1) kconv<AA, BB, TT, TRR, TXX, KGG, 1><<<gr, blk, 0, s>>>(out, feat, nbrT, Wt, att, st, g, b, N, nstat); \
        else if (mode == 2) kconv<AA, BB, TT, TRR, TXX, KGG, 2><<<gr, blk, 0, s>>>(out, feat, nbrT, Wt, att, st, g, b, N, nstat); \
        else kconv<AA, BB, TT, TRR, TXX, KGG, 3><<<gr, blk, 0, s>>>(out, feat, nbrT, Wt, att, st, g, b, N, nstat); \
    }
    if (false) {}
    CASE(16, 16, 27, 128, 8, 1)    // L0 subs + ppn3
    CASE(16, 32, 8, 128, 8, 1)     // down0
    CASE(80, 80, 27, 32, 16, 9)    // ppn1
    CASE(64, 80, 8, 32, 16, 4)     // down3
#undef CASE
}

// MFMA-path dispatcher; epi: 0 store, 1 store+res, 2 atomic (zero arg: memset first)
static void convm(hipStream_t s, float* out, const unsigned short* P, const int* nbrT,
                  const unsigned short* Wp, const float* res, int N, int A, int B,
                  int TAPS, int epi, bool zero) {
#define CASEM(AA, BB, TT, KGG)                                                             \
    else if (A == AA && B == BB && TAPS == TT) {                                           \
        if (zero) hipMemsetAsync(out, 0, (size_t)N * BB * 4, s);                           \
        dim3 gr(cdiv(N, 64), KGG), blk(256);                                               \
        if (epi == 0) kconvm<AA, BB, TT, KGG, 0><<<gr, blk, 0, s>>>(out, P, nbrT, Wp, res, N); \
        else if (epi == 1) kconvm<AA, BB, TT, KGG, 1><<<gr, blk, 0, s>>>(out, P, nbrT, Wp, res, N); \
        else kconvm<AA, BB, TT, KGG, 2><<<gr, blk, 0, s>>>(out, P, nbrT, Wp, res, N);      \
    }
    if (false) {}
    CASEM(32, 32, 27, 1)    // L1 subs
    CASEM(48, 48, 27, 1)    // L2 subs + ppn2
    CASEM(64, 64, 27, 3)    // L3 subs (atomic)
    CASEM(32, 48, 8, 1)     // down1
    CASEM(48, 64, 8, 2)     // down2 (atomic)
#undef CASEM
}

static void fprep(hipStream_t s, unsigned short* P, const float* x, int N, int A,
                  int mode, const double* st, const float* g, const float* b,
                  const float* att, int nstat) {
    int Ap = apad(A);
    kfprep<<<cdiv((long)N * Ap, TPB), TPB, 0, s>>>(P, x, N, A, Ap, st, g, b, att, mode, nstat);
}

extern "C" void kernel_launch(void* const* d_in, const int* in_sizes, int n_in,
                              void* d_out, int out_size, void* d_ws, size_t ws_size,
                              hipStream_t stream) {
    (void)n_in; (void)out_size; (void)ws_size;
    const int SL[5] = {192, 96, 48, 24, 12};
    const int C[5] = {16, 32, 48, 64, 80};
    int N[5];
    const int* coords[5];
    for (int l = 0; l < 5; l++) { N[l] = in_sizes[l] / 3; coords[l] = (const int*)d_in[l]; }
    const float* features = (const float*)d_in[5];
    const float* w_in = (const float*)d_in[6];
    const float *blk_w[4], *blk_g[4], *blk_b[4], *dn_g[4], *dn_b[4], *dn_w[4];
    for (int i = 0; i < 4; i++) {
        blk_w[i] = (const float*)d_in[7 + 6 * i];
        blk_g[i] = (const float*)d_in[8 + 6 * i];
        blk_b[i] = (const float*)d_in[9 + 6 * i];
        dn_g[i] = (const float*)d_in[10 + 6 * i];
        dn_b[i] = (const float*)d_in[11 + 6 * i];
        dn_w[i] = (const float*)d_in[12 + 6 * i];
    }
    const float* ppn1_w  = (const float*)d_in[31];
    const float* ppn1_sw = (const float*)d_in[32];
    const float* ppn2_w  = (const float*)d_in[33];
    const float* ppn2_sw = (const float*)d_in[34];
    const float* ppn3_w  = (const float*)d_in[35];
    const float* ppn3_pw = (const float*)d_in[36];
    const float* ppn3_sw = (const float*)d_in[37];
    float* dout = (float*)d_out;

    // ---- workspace ----
    char* ws = (char*)d_ws;
    size_t off = 0;
    auto alloc = [&](size_t bytes) -> char* {
        off = (off + 255) & ~(size_t)255;
        char* p = ws + off;
        off += bytes;
        return p;
    };
    int* nbrT[5];
    for (int l = 0; l < 5; l++) nbrT[l] = (int*)alloc((size_t)N[l] * 27 * 4);
    int* dnT[4];
    for (int i = 0; i < 4; i++) dnT[i] = (int*)alloc((size_t)N[i + 1] * 8 * 4);
    int* up1 = (int*)alloc((size_t)N[2] * 4);
    int* up2 = (int*)alloc((size_t)N[0] * 4);
    double* stats = (double*)alloc(26 * 160 * sizeof(double));
    // fp32 weights for fp32-path shapes
    float* blk0Wt = (float*)alloc((size_t)108 * 16 * 16 * 4);
    float* dn0Wt = (float*)alloc((size_t)8 * 16 * 32 * 4);
    float* dn3Wt = (float*)alloc((size_t)8 * 64 * 80 * 4);
    float* p1Wt = (float*)alloc((size_t)27 * 80 * 80 * 4);
    float* p3Wt = (float*)alloc((size_t)27 * 16 * 16 * 4);
    // packed bf16 weights for MFMA shapes: [k][b][3][Apad]
    unsigned short* blkWp[4];
    blkWp[1] = (unsigned short*)alloc((size_t)108 * 32 * 3 * apad(32) * 2);
    blkWp[2] = (unsigned short*)alloc((size_t)108 * 48 * 3 * apad(48) * 2);
    blkWp[3] = (unsigned short*)alloc((size_t)108 * 64 * 3 * apad(64) * 2);
    unsigned short* dn1Wp = (unsigned short*)alloc((size_t)8 * 48 * 3 * apad(32) * 2);
    unsigned short* dn2Wp = (unsigned short*)alloc((size_t)8 * 64 * 3 * apad(48) * 2);
    unsigned short* p2Wp = (unsigned short*)alloc((size_t)27 * 48 * 3 * apad(48) * 2);
    float* fmap0 = (float*)alloc((size_t)N[0] * 16 * 4);
    float* fmap2 = (float*)alloc((size_t)N[2] * 48 * 4);
    float* sc1 = (float*)alloc((size_t)N[4] * 2 * 4);
    float* sc2 = (float*)alloc((size_t)N[2] * 2 * 4);
    float* att1 = (float*)alloc((size_t)N[2] * 4);
    float* att2 = (float*)alloc((size_t)N[0] * 4);
    // packed feature buffer (max over MFMA convs of N*3*Apad*2)
    size_t pmax = 0;
    {
        size_t c1 = (size_t)N[1] * 3 * apad(32) * 2;
        size_t c2 = (size_t)N[2] * 3 * apad(48) * 2;
        size_t c3 = (size_t)N[3] * 3 * apad(64) * 2;
        pmax = c1 > c2 ? c1 : c2; if (c3 > pmax) pmax = c3;
    }
    unsigned short* P = (unsigned short*)alloc(pmax);

    // transient region: grids alias the 2 rotating fp32 feature buffers
    size_t BIG = 0;
    for (int l = 0; l < 5; l++) {
        size_t s = (size_t)N[l] * C[l] * 4;
        if (s > BIG) BIG = s;
    }
    BIG = (BIG + 255) & ~(size_t)255;
    off = (off + 255) & ~(size_t)255;
    size_t trans = off;
    int* grid[5];
    size_t gtot = 0;
    for (int l = 0; l < 5; l++) {
        grid[l] = (int*)(ws + trans + gtot);
        gtot += (size_t)SL[l] * SL[l] * SL[l] * 4;
    }
    float* B0 = (float*)(ws + trans);
    float* B1 = (float*)(ws + trans + BIG);

    // ---- phase 1 ----
    hipMemsetAsync(ws + trans, 0xFF, gtot, stream);
    hipMemsetAsync(stats, 0, 26 * 160 * sizeof(double), stream);
    for (int l = 0; l < 5; l++)
        kscatter<<<cdiv(N[l], TPB), TPB, 0, stream>>>(grid[l], coords[l], N[l], SL[l]);
    for (int l = 0; l < 5; l++)
        knbr27<<<cdiv((long)N[l] * 27, TPB), TPB, 0, stream>>>(nbrT[l], coords[l], grid[l], N[l], SL[l]);
    for (int i = 0; i < 4; i++)
        kdown8<<<cdiv((long)N[i + 1] * 8, TPB), TPB, 0, stream>>>(dnT[i], coords[i + 1], grid[i], N[i + 1], SL[i]);
    kup<<<cdiv(N[2], TPB), TPB, 0, stream>>>(up1, coords[2], grid[4], N[2], 12);
    kup<<<cdiv(N[0], TPB), TPB, 0, stream>>>(up2, coords[0], grid[2], N[0], 48);
    // fp32 weight transposes
    ktrans<<<cdiv(108 * 256, TPB), TPB, 0, stream>>>(blk0Wt, blk_w[0], 108, 16, 16);
    ktrans<<<cdiv(8 * 512, TPB), TPB, 0, stream>>>(dn0Wt, dn_w[0], 8, 16, 32);
    ktrans<<<cdiv(8 * 5120, TPB), TPB, 0, stream>>>(dn3Wt, dn_w[3], 8, 64, 80);
    ktrans<<<cdiv(27 * 6400, TPB), TPB, 0, stream>>>(p1Wt, ppn1_w, 27, 80, 80);
    ktrans<<<cdiv(27 * 256, TPB), TPB, 0, stream>>>(p3Wt, ppn3_w, 27, 16, 16);
    // bf16 packed weights
    kwprep<<<cdiv((long)108 * 32 * apad(32), TPB), TPB, 0, stream>>>(blkWp[1], blk_w[1], 108, 32, 32, apad(32));
    kwprep<<<cdiv((long)108 * 48 * apad(48), TPB), TPB, 0, stream>>>(blkWp[2], blk_w[2], 108, 48, 48, apad(48));
    kwprep<<<cdiv((long)108 * 64 * apad(64), TPB), TPB, 0, stream>>>(blkWp[3], blk_w[3], 108, 64, 64, apad(64));
    kwprep<<<cdiv((long)8 * 48 * apad(32), TPB), TPB, 0, stream>>>(dn1Wp, dn_w[1], 8, 32, 48, apad(32));
    kwprep<<<cdiv((long)8 * 64 * apad(48), TPB), TPB, 0, stream>>>(dn2Wp, dn_w[2], 8, 48, 64, apad(48));
    kwprep<<<cdiv((long)27 * 48 * apad(48), TPB), TPB, 0, stream>>>(p2Wp, ppn2_w, 27, 48, 48, apad(48));

    // ---- phase 2 ----
    int slot = 0;
    auto st = [&]() { return stats + 160 * (slot++); };

    float* X = B0;
    float* Y = B1;
    kconv_in<<<cdiv((long)N[0] * 4, TPB), TPB, 0, stream>>>(X, features, nbrT[0], w_in, N[0]);
    hipMemcpyAsync(fmap0, X, (size_t)N[0] * 16 * 4, hipMemcpyDeviceToDevice, stream);

    for (int i = 0; i < 4; i++) {
        int Ni = N[i], Ci = C[i];
        int shb = 8 * Ci * 2 * (int)sizeof(double);
        bool mf = (i >= 1);                    // MFMA path for A in {32,48,64}
        size_t wstride = (size_t)27 * Ci * 3 * apad(Ci);
        for (int r = 0; r < 2; r++) {
            double* s0 = st();
            kstats<<<cdiv(Ni, 256), 4 * Ci, shb, stream>>>(s0, X, Ni, Ci);
            if (mf) {
                fprep(stream, P, X, Ni, Ci, 1, s0, blk_g[i] + (2 * r) * Ci, blk_b[i] + (2 * r) * Ci, nullptr, Ni);
                // conv1 -> Y (L3: atomic KG, memset)
                convm(stream, Y, P, nbrT[i], blkWp[i] + (size_t)(2 * r) * wstride,
                      nullptr, Ni, Ci, Ci, 27, (i == 3) ? 2 : 0, (i == 3));
            } else {
                convf(stream, Y, X, nbrT[i], blk0Wt + (size_t)(2 * r) * 27 * 256,
                      Ni, Ci, Ci, 27, 1, nullptr, s0, blk_g[i] + (2 * r) * Ci, blk_b[i] + (2 * r) * Ci, Ni);
            }
            double* s1 = st();
            kstats<<<cdiv(Ni, 256), 4 * Ci, shb, stream>>>(s1, Y, Ni, Ci);
            if (mf) {
                fprep(stream, P, Y, Ni, Ci, 1, s1, blk_g[i] + (2 * r + 1) * Ci, blk_b[i] + (2 * r + 1) * Ci, nullptr, Ni);
                // conv2 -> X with residual (L3: atomic onto resident X)
                convm(stream, X, P, nbrT[i], blkWp[i] + (size_t)(2 * r + 1) * wstride,
                      X, Ni, Ci, Ci, 27, (i == 3) ? 2 : 1, false);
            } else {
                convf(stream, X, Y, nbrT[i], blk0Wt + (size_t)(2 * r + 1) * 27 * 256,
                      Ni, Ci, Ci, 27, 2, nullptr, s1, blk_g[i] + (2 * r + 1) * Ci, blk_b[i] + (2 * r + 1) * Ci, Ni);
            }
        }
        double* s4 = st();
        kstats<<<cdiv(Ni, 256), 4 * Ci, shb, stream>>>(s4, X, Ni, Ci);
        if (i == 0) {
            convf(stream, Y, X, dnT[0], dn0Wt, N[1], 16, 32, 8, 1, nullptr, s4, dn_g[0], dn_b[0], Ni);
        } else if (i == 1) {
            fprep(stream, P, X, Ni, 32, 1, s4, dn_g[1], dn_b[1], nullptr, Ni);
            convm(stream, Y, P, dnT[1], dn1Wp, nullptr, N[2], 32, 48, 8, 0, false);
        } else if (i == 2) {
            fprep(stream, P, X, Ni, 48, 1, s4, dn_g[2], dn_b[2], nullptr, Ni);
            convm(stream, Y, P, dnT[2], dn2Wp, nullptr, N[3], 48, 64, 8, 2, true);
        } else {
            convf(stream, Y, X, dnT[3], dn3Wt, N[4], 64, 80, 8, 1, nullptr, s4, dn_g[3], dn_b[3], Ni);
        }
        if (i == 1)
            hipMemcpyAsync(fmap2, Y, (size_t)N[2] * 48 * 4, hipMemcpyDeviceToDevice, stream);
        float* t = X; X = Y; Y = t;
    }

    // ---- heads ---- (X = level-4 features, 80-wide)
    convf(stream, Y, X, nbrT[4], p1Wt, N[4], 80, 80, 27, 0, nullptr, nullptr, nullptr, nullptr, N[4]);
    kscores<<<cdiv(N[4], TPB), TPB, 0, stream>>>(sc1, Y, ppn1_sw, N[4], 80);
    koutc<<<cdiv(N[4], TPB), TPB, 0, stream>>>(dout + (size_t)N[0] * 5, coords[4], sc1, N[4]);
    // ppn2 @ level 2: attention fused into prep
    katt<<<cdiv(N[2], TPB), TPB, 0, stream>>>(att1, up1, sc1, N[2]);
    fprep(stream, P, fmap2, N[2], 48, 2, nullptr, nullptr, nullptr, att1, N[2]);
    convm(stream, X, P, nbrT[2], p2Wp, nullptr, N[2], 48, 48, 27, 0, false);
    kscores<<<cdiv(N[2], TPB), TPB, 0, stream>>>(sc2, X, ppn2_sw, N[2], 48);
    koutc<<<cdiv(N[2], TPB), TPB, 0, stream>>>(dout + (size_t)(N[0] + N[4]) * 5, coords[2], sc2, N[2]);
    // ppn3 @ level 0: fp32 path with att in staging
    katt<<<cdiv(N[0], TPB), TPB, 0, stream>>>(att2, up2, sc2, N[0]);
    convf(stream, Y, fmap0, nbrT[0], p3Wt, N[0], 16, 16, 27, 3, att2, nullptr, nullptr, nullptr, N[0]);
    kout0<<<cdiv(N[0], TPB), TPB, 0, stream>>>(dout, Y, ppn3_pw, ppn3_sw, N[0]);
}